// Round 10
// baseline (333.971 us; speedup 1.0000x reference)
//
#include <hip/hip_runtime.h>

// Peeling propagation on bipartite graph. V=1e6, F=4.2e6, K=3 (edge e -> function e/3).
// T=5. Output: deg (V floats) in d_out.
//
// R18 = R17 plus accum grid-shape fix:
//  * CH_BITS 12->11 (chunk = 2048 vars): k_accum goes 245 blocks (0.96/CU, 16 waves/CU)
//    -> 489 blocks (1.9/CU, ~31 waves/CU). Same total work, near-full residency.
//    Sort entry encode: vlocal:11 | sign<<11 (12 of 16 bits used).
// Banked: grid.sync ~240us (R12); scattered global atomics ~32B HBM write each (R14);
// pack_sort is latency/ramp-shaped at ~64us (R16/R17: FETCH -16MB, occupancy +8% both
// no-ops); filter granularity 8->4 vars: no-op (R17). Dispatch floor = 2 + 2*Tn.

static constexpr int Vn = 1000000;
static constexpr int Fn = 4200000;
static constexpr int Tn = 5;

static constexpr int SBLK = 2048;                          // sort blocks / regions
static constexpr int FPB  = 2052;                          // functions/block (mult of 4)
static constexpr int BIN_BITS = 10;                        // fine bin = 1024 vars
static constexpr int BIN_SIZE = 1 << BIN_BITS;
static constexpr int NB  = (Vn + BIN_SIZE - 1) >> BIN_BITS;   // 977 fine bins
static constexpr int NBP = 1024;                           // padded fine-bin count (scan)
static constexpr int CH_BITS = 11;                         // chunk = 2048 vars (accum)
static constexpr int CH_SIZE = 1 << CH_BITS;
static constexpr int NCH = (Vn + CH_SIZE - 1) >> CH_BITS;  // 489 chunks
static constexpr int RCAP = 3 * FPB;                       // 6156 max entries/region
static constexpr int RSTRIDE = (RCAP + 63) & ~63;          // 6208 -> 128B-aligned regions
static constexpr int OROW = 1024;                          // offs row stride (u16)
static constexpr int AVW = NCH * (CH_SIZE / 64);           // 15648 u64 mask words (16B-mult)

// ---- fused pack + histogram + shuffle-scan + register-carried scatter + flush ----
__global__ __launch_bounds__(256) void k_pack_sort(
    const int* __restrict__ vidx, const float* __restrict__ ef,
    const float* __restrict__ afunc,
    unsigned long long* __restrict__ gpack,
    unsigned short* __restrict__ offs,      // [SBLK][OROW] exclusive fine-bin offsets
    unsigned short* __restrict__ sorted)    // [SBLK][RSTRIDE] block-private regions
{
    __shared__ unsigned int cur[NBP];       // pass1: histogram; after scan: cursors
    __shared__ unsigned int wsum[4];
    __shared__ unsigned int s_total;
    __shared__ __align__(16) unsigned short st[RSTRIDE];   // 12.4 KB staged region

    const int k = blockIdx.x;
    const int f0 = k * FPB;
    int n = Fn - f0; if (n < 0) n = 0; if (n > FPB) n = FPB;
    const int n4 = n >> 2;                  // n % 4 == 0 always (Fn, FPB mult of 4)
    const int t = threadIdx.x;

    for (int i = t; i < NBP; i += 256) cur[i] = 0u;
    __syncthreads();

    // pass 1: <=3 quad-iterations per thread; packed words kept in registers.
    const int j0 = t, j1 = t + 256, j2 = t + 512;
    const bool has0 = j0 < n4, has1 = j1 < n4, has2 = j2 < n4;
    unsigned long long q0a=0,q0b=0,q0c=0,q0d=0, q1a=0,q1b=0,q1c=0,q1d=0, q2a=0,q2b=0,q2c=0,q2d=0;

#define PROC(J, QA, QB, QC, QD) do {                                               \
    const int fb = f0 + 4 * (J), e = 3 * fb;                                       \
    int4 va = *(const int4*)(vidx + e);                                            \
    int4 vb = *(const int4*)(vidx + e + 4);                                        \
    int4 vc = *(const int4*)(vidx + e + 8);                                        \
    float4 ea = *(const float4*)(ef + e);                                          \
    float4 eb = *(const float4*)(ef + e + 4);                                      \
    float4 ec = *(const float4*)(ef + e + 8);                                      \
    float4 a4 = *(const float4*)(afunc + fb);                                      \
    int   vv[12] = {va.x,va.y,va.z,va.w,vb.x,vb.y,vb.z,vb.w,vc.x,vc.y,vc.z,vc.w};  \
    float ss[12] = {ea.x,ea.y,ea.z,ea.w,eb.x,eb.y,eb.z,eb.w,ec.x,ec.y,ec.z,ec.w};  \
    float aa[4]  = {a4.x,a4.y,a4.z,a4.w};                                          \
    unsigned long long gq[4];                                                      \
    _Pragma("unroll")                                                              \
    for (int q = 0; q < 4; ++q) {                                                  \
        int v0 = vv[3*q], v1 = vv[3*q+1], v2 = vv[3*q+2];                          \
        unsigned int s0 = ss[3*q]   > 0.0f ? 1u : 0u;                              \
        unsigned int s1 = ss[3*q+1] > 0.0f ? 1u : 0u;                              \
        unsigned int s2 = ss[3*q+2] > 0.0f ? 1u : 0u;                              \
        unsigned int act = aa[q] != 0.0f ? 1u : 0u;                                \
        gq[q] = (unsigned long long)(unsigned int)v0                               \
              | ((unsigned long long)(unsigned int)v1 << 20)                       \
              | ((unsigned long long)(unsigned int)v2 << 40)                       \
              | ((unsigned long long)s0 << 60)                                     \
              | ((unsigned long long)s1 << 61)                                     \
              | ((unsigned long long)s2 << 62)                                     \
              | ((unsigned long long)act << 63);                                   \
        if (act) {                                                                 \
            atomicAdd(&cur[v0 >> BIN_BITS], 1u);                                   \
            atomicAdd(&cur[v1 >> BIN_BITS], 1u);                                   \
            atomicAdd(&cur[v2 >> BIN_BITS], 1u);                                   \
        }                                                                          \
    }                                                                              \
    *(ulonglong2*)(gpack + fb)     = make_ulonglong2(gq[0], gq[1]);                \
    *(ulonglong2*)(gpack + fb + 2) = make_ulonglong2(gq[2], gq[3]);                \
    QA = gq[0]; QB = gq[1]; QC = gq[2]; QD = gq[3];                                \
} while (0)

    if (has0) PROC(j0, q0a, q0b, q0c, q0d);
    if (has1) PROC(j1, q1a, q1b, q1c, q1d);
    if (has2) PROC(j2, q2a, q2b, q2c, q2d);
#undef PROC
    __syncthreads();

    // shuffle-based exclusive scan over 1024 fine bins (256 threads x 4 bins).
    {
        const int lane = t & 63, wid = t >> 6;
        unsigned int a0 = cur[4 * t], a1 = cur[4 * t + 1];
        unsigned int a2 = cur[4 * t + 2], a3 = cur[4 * t + 3];
        unsigned int tsum = a0 + a1 + a2 + a3;
        unsigned int x = tsum;
        #pragma unroll
        for (int off = 1; off < 64; off <<= 1) {
            unsigned int y = (unsigned int)__shfl_up((int)x, off);
            if (lane >= off) x += y;
        }
        if (lane == 63) wsum[wid] = x;
        __syncthreads();
        unsigned int wbase = 0;
        for (int w = 0; w < wid; ++w) wbase += wsum[w];
        unsigned int e0x = wbase + x - tsum;      // exclusive prefix of bin 4t
        unsigned int e1x = e0x + a0, e2x = e1x + a1, e3x = e2x + a2;
        cur[4 * t] = e0x; cur[4 * t + 1] = e1x; cur[4 * t + 2] = e2x; cur[4 * t + 3] = e3x;
        if (t == 255) s_total = e3x + a3;         // inclusive total (= #active entries)
        unsigned short* row = offs + (size_t)k * OROW;
        if (4 * t     <= NB) row[4 * t]     = (unsigned short)e0x;
        if (4 * t + 1 <= NB) row[4 * t + 1] = (unsigned short)e1x;
        if (4 * t + 2 <= NB) row[4 * t + 2] = (unsigned short)e2x;
        if (4 * t + 3 <= NB) row[4 * t + 3] = (unsigned short)e3x;
    }
    __syncthreads();

    // pass 2: scatter from registers; entry = 11-bit chunk-local v | sign<<11
#define SCAT1(G) do {                                                              \
    unsigned long long g = (G);                                                    \
    if ((long long)g < 0) {                                                        \
        unsigned int v0 = (unsigned int)(g & 0xFFFFFu);                            \
        unsigned int v1 = (unsigned int)((g >> 20) & 0xFFFFFu);                    \
        unsigned int v2 = (unsigned int)((g >> 40) & 0xFFFFFu);                    \
        unsigned int sl0 = atomicAdd(&cur[v0 >> BIN_BITS], 1u);                    \
        st[sl0] = (unsigned short)((v0 & (CH_SIZE-1)) | ((unsigned int)((g >> 60) & 1u) << CH_BITS)); \
        unsigned int sl1 = atomicAdd(&cur[v1 >> BIN_BITS], 1u);                    \
        st[sl1] = (unsigned short)((v1 & (CH_SIZE-1)) | ((unsigned int)((g >> 61) & 1u) << CH_BITS)); \
        unsigned int sl2 = atomicAdd(&cur[v2 >> BIN_BITS], 1u);                    \
        st[sl2] = (unsigned short)((v2 & (CH_SIZE-1)) | ((unsigned int)((g >> 62) & 1u) << CH_BITS)); \
    }                                                                              \
} while (0)
    if (has0) { SCAT1(q0a); SCAT1(q0b); SCAT1(q0c); SCAT1(q0d); }
    if (has1) { SCAT1(q1a); SCAT1(q1b); SCAT1(q1c); SCAT1(q1d); }
    if (has2) { SCAT1(q2a); SCAT1(q2b); SCAT1(q2c); SCAT1(q2d); }
#undef SCAT1
    __syncthreads();

    // coalesced flush: LDS region -> global, 16B vectors (slack beyond total never read)
    {
        const int tot = (int)s_total;
        const int nvec = (tot + 7) >> 3;               // 8 u16 per int4
        int4* __restrict__ dst = (int4*)(sorted + (size_t)k * RSTRIDE);  // RSTRIDE*2 % 16 == 0
        const int4* __restrict__ src = (const int4*)st;
        for (int i = t; i < nvec; i += 256) dst[i] = src[i];
    }
}

// 4-var-granular dirty mask from a 64-bit singles word: bit j = (nibble j of m) != 0
__device__ __forceinline__ unsigned short subdirty4(unsigned long long m) {
    unsigned int r = 0;
    #pragma unroll
    for (int j = 0; j < 16; ++j)
        r |= (((m >> (4 * j)) & 0xFull) ? 1u : 0u) << j;
    return (unsigned short)r;
}

// ---- per-chunk (2048 vars) accumulate + decode + tmp/tgrp zeroing epilogue ----
__global__ __launch_bounds__(1024) void k_accum(
    const unsigned short* __restrict__ offs,     // [SBLK][OROW]
    const unsigned short* __restrict__ sorted,
    const float* __restrict__ avars,
    unsigned int* __restrict__ packed,
    unsigned long long* __restrict__ avm,
    unsigned long long* __restrict__ svm,
    unsigned short* __restrict__ sgrp4,
    unsigned int* __restrict__ tmp,
    unsigned char* __restrict__ tgrp)
{
    __shared__ unsigned int acc[CH_SIZE];        // 8 KB
    __shared__ unsigned short row0[SBLK];        // 4 KB
    __shared__ unsigned short row1[SBLK];        // 4 KB
    const int c = blockIdx.x;                    // chunk 0..488 (2 fine bins each)
    const int r0 = 2 * c;
    const int r1 = (2 * c + 2 < NB) ? (2 * c + 2) : NB;
    for (int i = threadIdx.x; i < CH_SIZE; i += 1024) acc[i] = 0u;
    for (int i = threadIdx.x; i < SBLK; i += 1024) {   // strided gather of 2 offs columns
        row0[i] = offs[(size_t)i * OROW + r0];
        row1[i] = offs[(size_t)i * OROW + r1];
    }
    __syncthreads();
    for (int k = threadIdx.x; k < SBLK; k += 1024) {   // 2 regions per thread
        const int s0 = row0[k], s1 = row1[k];
        const unsigned short* seg = sorted + (size_t)k * RSTRIDE;  // 128B-aligned base
        int e = s0;
        for (; e < s1 && (e & 3); ++e) {               // head to 8B alignment
            unsigned int p = seg[e];
            atomicAdd(&acc[p & (CH_SIZE - 1)], 0x10000u | (p >> CH_BITS));
        }
        for (; e + 4 <= s1; e += 4) {                  // 4 entries per u64 load
            unsigned long long q = *(const unsigned long long*)(seg + e);
            #pragma unroll
            for (int j = 0; j < 4; ++j) {
                unsigned int p = (unsigned int)((q >> (16 * j)) & 0xFFFFu);
                atomicAdd(&acc[p & (CH_SIZE - 1)], 0x10000u | (p >> CH_BITS));
            }
        }
        for (; e < s1; ++e) {                          // tail
            unsigned int p = seg[e];
            atomicAdd(&acc[p & (CH_SIZE - 1)], 0x10000u | (p >> CH_BITS));
        }
    }
    __syncthreads();
    const int vbase = c << CH_BITS;
    for (int i = threadIdx.x; i < CH_SIZE; i += 1024) {
        int v = vbase + i;
        bool valid = v < Vn;
        unsigned int p = valid ? acc[i] : 0u;
        bool av = valid && (avars[v] != 0.0f);
        unsigned int cnt = p >> 16, pos = p & 0xFFFFu;
        bool sv = av && (pos == 0u || pos == cnt);    // deg == |sdeg|
        unsigned long long avb = __ballot(av);
        unsigned long long svb = __ballot(sv);
        if (valid) { packed[v] = p; tmp[v] = 0u; }    // tmp zeroed here (rides the pass)
        if ((threadIdx.x & 63) == 0) {                // word index < AVW (chunk-padded)
            avm[v >> 6] = avb;
            svm[v >> 6] = svb;
            sgrp4[v >> 6] = subdirty4(svb);           // 4-var-granular dirty bits
            tgrp[v >> 6] = 0;
        }
    }
}

// ---- iteration: function side. LDS sgrp4 filter then fine bitmask. ----
__device__ __forceinline__ void fire_one(unsigned long long g, int f,
                                         unsigned long long* __restrict__ gpack,
                                         const unsigned int* __restrict__ svm32,
                                         const unsigned short* __restrict__ s4,  // LDS
                                         unsigned int* __restrict__ tmp,
                                         unsigned char* __restrict__ tgrp)
{
    if ((long long)g >= 0) return;               // inactive (bit63 clear)
    unsigned int v0 = (unsigned int)(g & 0xFFFFFu);
    unsigned int v1 = (unsigned int)((g >> 20) & 0xFFFFFu);
    unsigned int v2 = (unsigned int)((g >> 40) & 0xFFFFFu);
    // LDS-resident 4-var-granular filter: no global transactions on the common path
    unsigned int h0 = (unsigned int)(s4[v0 >> 6] >> ((v0 >> 2) & 15u)) & 1u;
    unsigned int h1 = (unsigned int)(s4[v1 >> 6] >> ((v1 >> 2) & 15u)) & 1u;
    unsigned int h2 = (unsigned int)(s4[v2 >> 6] >> ((v2 >> 2) & 15u)) & 1u;
    if (!(h0 | h1 | h2)) return;
    unsigned int hit = ((svm32[v0 >> 5] >> (v0 & 31u)) |
                        (svm32[v1 >> 5] >> (v1 & 31u)) |
                        (svm32[v2 >> 5] >> (v2 & 31u))) & 1u;
    if (!hit) return;
    gpack[f] = g & ~(1ull << 63);                // function deactivates (single_f = 1)
    atomicAdd(&tmp[v0], 0x10000u | (unsigned int)((g >> 60) & 1u));
    atomicAdd(&tmp[v1], 0x10000u | (unsigned int)((g >> 61) & 1u));
    atomicAdd(&tmp[v2], 0x10000u | (unsigned int)((g >> 62) & 1u));
    tgrp[v0 >> 6] = 1; tgrp[v1 >> 6] = 1; tgrp[v2 >> 6] = 1;
}

static constexpr int FBLOCKS = 1024;             // grid-stride blocks (4/CU)

__global__ __launch_bounds__(256) void k_funcs(unsigned long long* __restrict__ gpack,
                        const unsigned int* __restrict__ svm32,
                        const unsigned short* __restrict__ sgrp4,
                        unsigned int* __restrict__ tmp,
                        unsigned char* __restrict__ tgrp)
{
    __shared__ __align__(16) unsigned short s4[AVW];       // 31.3 KB, AVW % 8 == 0
    for (int i = threadIdx.x; i < AVW / 8; i += 256)
        ((int4*)s4)[i] = ((const int4*)sgrp4)[i];
    __syncthreads();
    const int step = FBLOCKS * 256 * 8;
    for (int f = (blockIdx.x * 256 + threadIdx.x) * 8; f < Fn; f += step) {
        // Fn % 8 == 0: each 8-group is full
        ulonglong2 ga = *(const ulonglong2*)(gpack + f);   // 16B aligned
        ulonglong2 gb = *(const ulonglong2*)(gpack + f + 2);
        ulonglong2 gc = *(const ulonglong2*)(gpack + f + 4);
        ulonglong2 gd = *(const ulonglong2*)(gpack + f + 6);
        fire_one(ga.x, f,     gpack, svm32, s4, tmp, tgrp);
        fire_one(ga.y, f + 1, gpack, svm32, s4, tmp, tgrp);
        fire_one(gb.x, f + 2, gpack, svm32, s4, tmp, tgrp);
        fire_one(gb.y, f + 3, gpack, svm32, s4, tmp, tgrp);
        fire_one(gc.x, f + 4, gpack, svm32, s4, tmp, tgrp);
        fire_one(gc.y, f + 5, gpack, svm32, s4, tmp, tgrp);
        fire_one(gd.x, f + 6, gpack, svm32, s4, tmp, tgrp);
        fire_one(gd.y, f + 7, gpack, svm32, s4, tmp, tgrp);
    }
}

// ---- iteration: variable side. Clean-word early-exit; masks + sgrp4 refresh. ----
__global__ void k_update(unsigned int* __restrict__ packed,
                         unsigned int* __restrict__ tmp,
                         unsigned long long* __restrict__ avm,
                         unsigned long long* __restrict__ svm,
                         unsigned short* __restrict__ sgrp4,
                         unsigned char* __restrict__ tgrp,
                         float* __restrict__ deg, int write_deg)
{
    const int v = blockIdx.x * blockDim.x + threadIdx.x;
    const int lane = threadIdx.x & 63;
    const bool valid = v < Vn;
    unsigned long long avw = 0ull, svw = 0ull;
    unsigned char tg = 0;
    if (valid) {
        avw = avm[v >> 6]; svw = svm[v >> 6];          // wave-broadcast loads
        tg = tgrp[v >> 6];                             // wave-uniform dirty-group byte
    }
    // clean word: no fired updates, no singles to retire -> provably no state change
    if (!write_deg && !tg && svw == 0ull) return;
    const bool av_old = valid && ((avw >> lane) & 1ull);
    const bool sv     = valid && ((svw >> lane) & 1ull);
    const bool av_new = av_old && !sv;                  // av *= (1 - single_v)
    unsigned int p = 0u;
    if (valid) {
        p = packed[v];
        if (tg) {
            unsigned int tp = tmp[v];
            if (tp != 0u) {
                if (av_old) { p -= tp; packed[v] = p; } // deg -= seg*av (field-safe)
                tmp[v] = 0u;
            }
        }
    }
    const unsigned int c = p >> 16, pos = p & 0xFFFFu;
    const bool nsv = av_new && (pos == 0u || pos == c); // next single_v
    unsigned long long nsvb = __ballot(nsv);
    if (lane == 0 && valid) {
        svm[v >> 6] = nsvb;
        avm[v >> 6] = avw & ~svw;
        sgrp4[v >> 6] = subdirty4(nsvb);
        if (tg) tgrp[v >> 6] = 0;
    }
    if (write_deg && valid) deg[v] = (float)c;
}

extern "C" void kernel_launch(void* const* d_in, const int* in_sizes, int n_in,
                              void* d_out, int out_size, void* d_ws, size_t ws_size,
                              hipStream_t stream) {
    const int*   graph_map        = (const int*)d_in[0];   // row0 = vidx
    const float* edge_feature     = (const float*)d_in[1];
    const float* active_variables = (const float*)d_in[2];
    const float* active_functions = (const float*)d_in[3];
    const int* vidx = graph_map;

    float* deg = (float*)d_out;
    char* ws = (char*)d_ws;
    size_t off = 0;
    auto alloc = [&](size_t bytes) -> void* {
        void* p = ws + off; off += (bytes + 255) & ~(size_t)255; return p;
    };
    unsigned long long* gpack = (unsigned long long*)alloc(8ull * Fn);            // 33.6 MB
    unsigned int* packed      = (unsigned int*)alloc(4ull * Vn);                  //  4.0 MB
    unsigned long long* avm   = (unsigned long long*)alloc(8ull * AVW);           //  125 KB
    unsigned long long* svm   = (unsigned long long*)alloc(8ull * AVW);           //  125 KB
    unsigned short* sgrp4     = (unsigned short*)alloc(2ull * AVW);               // 31.3 KB
    unsigned char* tgrp       = (unsigned char*)alloc(AVW);                       // 15.6 KB
    unsigned short* offs      = (unsigned short*)alloc(2ull * SBLK * OROW);       //  4.2 MB
    unsigned short* sorted    = (unsigned short*)alloc(2ull * SBLK * RSTRIDE);    // 25.4 MB
    unsigned int* tmp         = (unsigned int*)alloc(4ull * Vn);                  //  4.0 MB
    // total ~71.5 MB

    const int BS = 256;
    const int gV = (Vn + BS - 1) / BS;

    k_pack_sort<<<SBLK, 256, 0, stream>>>(vidx, edge_feature, active_functions,
                                          gpack, offs, sorted);
    k_accum<<<NCH, 1024, 0, stream>>>(offs, sorted, active_variables, packed,
                                      avm, svm, sgrp4, tmp, tgrp);
    for (int t = 0; t < Tn; ++t) {
        k_funcs<<<FBLOCKS, BS, 0, stream>>>(gpack, (const unsigned int*)svm, sgrp4, tmp, tgrp);
        k_update<<<gV, BS, 0, stream>>>(packed, tmp, avm, svm, sgrp4, tgrp, deg, (t == Tn - 1) ? 1 : 0);
    }
}

// Round 11
// 316.838 us; speedup vs baseline: 1.0541x; 1.0541x over previous
//
#include <hip/hip_runtime.h>

// Peeling propagation on bipartite graph. V=1e6, F=4.2e6, K=3 (edge e -> function e/3).
// T=5. Output: deg (V floats) in d_out.
//
// R19 = revert R18's CH_BITS=11 (span-count doubling doubled accum's cache-line
// over-fetch: FETCH 100->195MB, 30->70us; chunk granularity must stay >=4096),
// back to R16/R17 config (304.6us best), plus:
//  * k_funcs: 16 fns/thread, single sweep (8x ulonglong2 = 128B outstanding/thread).
//    k_funcs streams 33.6MB at only ~1.7TB/s -> issue/latency-limited; double MLP.
// Banked: grid.sync ~240us (R12); scattered global atomics ~32B HBM write each (R14);
// pack_sort latency-shaped at ~64us (R16/R17 probes no-op); dispatch floor 2+2*Tn.

static constexpr int Vn = 1000000;
static constexpr int Fn = 4200000;
static constexpr int Tn = 5;

static constexpr int SBLK = 2048;                          // sort blocks / regions
static constexpr int FPB  = 2052;                          // functions/block (mult of 4)
static constexpr int BIN_BITS = 10;                        // fine bin = 1024 vars
static constexpr int BIN_SIZE = 1 << BIN_BITS;
static constexpr int NB  = (Vn + BIN_SIZE - 1) >> BIN_BITS;   // 977 fine bins
static constexpr int NBP = 1024;                           // padded fine-bin count (scan)
static constexpr int CH_BITS = 12;                         // chunk = 4096 vars (accum)
static constexpr int CH_SIZE = 1 << CH_BITS;
static constexpr int NCH = (Vn + CH_SIZE - 1) >> CH_BITS;  // 245 chunks
static constexpr int RCAP = 3 * FPB;                       // 6156 max entries/region
static constexpr int RSTRIDE = (RCAP + 63) & ~63;          // 6208 -> 128B-aligned regions
static constexpr int OROW = 1024;                          // offs row stride (u16)
static constexpr int AVW = NCH * (CH_SIZE / 64);           // 15680 u64 mask words (16B-mult)

// ---- fused pack + histogram + shuffle-scan + register-carried scatter + flush ----
__global__ __launch_bounds__(256) void k_pack_sort(
    const int* __restrict__ vidx, const float* __restrict__ ef,
    const float* __restrict__ afunc,
    unsigned long long* __restrict__ gpack,
    unsigned short* __restrict__ offs,      // [SBLK][OROW] exclusive fine-bin offsets
    unsigned short* __restrict__ sorted)    // [SBLK][RSTRIDE] block-private regions
{
    __shared__ unsigned int cur[NBP];       // pass1: histogram; after scan: cursors
    __shared__ unsigned int wsum[4];
    __shared__ unsigned int s_total;
    __shared__ __align__(16) unsigned short st[RSTRIDE];   // 12.4 KB staged region

    const int k = blockIdx.x;
    const int f0 = k * FPB;
    int n = Fn - f0; if (n < 0) n = 0; if (n > FPB) n = FPB;
    const int n4 = n >> 2;                  // n % 4 == 0 always (Fn, FPB mult of 4)
    const int t = threadIdx.x;

    for (int i = t; i < NBP; i += 256) cur[i] = 0u;
    __syncthreads();

    // pass 1: <=3 quad-iterations per thread; packed words kept in registers.
    const int j0 = t, j1 = t + 256, j2 = t + 512;
    const bool has0 = j0 < n4, has1 = j1 < n4, has2 = j2 < n4;
    unsigned long long q0a=0,q0b=0,q0c=0,q0d=0, q1a=0,q1b=0,q1c=0,q1d=0, q2a=0,q2b=0,q2c=0,q2d=0;

#define PROC(J, QA, QB, QC, QD) do {                                               \
    const int fb = f0 + 4 * (J), e = 3 * fb;                                       \
    int4 va = *(const int4*)(vidx + e);                                            \
    int4 vb = *(const int4*)(vidx + e + 4);                                        \
    int4 vc = *(const int4*)(vidx + e + 8);                                        \
    float4 ea = *(const float4*)(ef + e);                                          \
    float4 eb = *(const float4*)(ef + e + 4);                                      \
    float4 ec = *(const float4*)(ef + e + 8);                                      \
    float4 a4 = *(const float4*)(afunc + fb);                                      \
    int   vv[12] = {va.x,va.y,va.z,va.w,vb.x,vb.y,vb.z,vb.w,vc.x,vc.y,vc.z,vc.w};  \
    float ss[12] = {ea.x,ea.y,ea.z,ea.w,eb.x,eb.y,eb.z,eb.w,ec.x,ec.y,ec.z,ec.w};  \
    float aa[4]  = {a4.x,a4.y,a4.z,a4.w};                                          \
    unsigned long long gq[4];                                                      \
    _Pragma("unroll")                                                              \
    for (int q = 0; q < 4; ++q) {                                                  \
        int v0 = vv[3*q], v1 = vv[3*q+1], v2 = vv[3*q+2];                          \
        unsigned int s0 = ss[3*q]   > 0.0f ? 1u : 0u;                              \
        unsigned int s1 = ss[3*q+1] > 0.0f ? 1u : 0u;                              \
        unsigned int s2 = ss[3*q+2] > 0.0f ? 1u : 0u;                              \
        unsigned int act = aa[q] != 0.0f ? 1u : 0u;                                \
        gq[q] = (unsigned long long)(unsigned int)v0                               \
              | ((unsigned long long)(unsigned int)v1 << 20)                       \
              | ((unsigned long long)(unsigned int)v2 << 40)                       \
              | ((unsigned long long)s0 << 60)                                     \
              | ((unsigned long long)s1 << 61)                                     \
              | ((unsigned long long)s2 << 62)                                     \
              | ((unsigned long long)act << 63);                                   \
        if (act) {                                                                 \
            atomicAdd(&cur[v0 >> BIN_BITS], 1u);                                   \
            atomicAdd(&cur[v1 >> BIN_BITS], 1u);                                   \
            atomicAdd(&cur[v2 >> BIN_BITS], 1u);                                   \
        }                                                                          \
    }                                                                              \
    *(ulonglong2*)(gpack + fb)     = make_ulonglong2(gq[0], gq[1]);                \
    *(ulonglong2*)(gpack + fb + 2) = make_ulonglong2(gq[2], gq[3]);                \
    QA = gq[0]; QB = gq[1]; QC = gq[2]; QD = gq[3];                                \
} while (0)

    if (has0) PROC(j0, q0a, q0b, q0c, q0d);
    if (has1) PROC(j1, q1a, q1b, q1c, q1d);
    if (has2) PROC(j2, q2a, q2b, q2c, q2d);
#undef PROC
    __syncthreads();

    // shuffle-based exclusive scan over 1024 fine bins (256 threads x 4 bins).
    {
        const int lane = t & 63, wid = t >> 6;
        unsigned int a0 = cur[4 * t], a1 = cur[4 * t + 1];
        unsigned int a2 = cur[4 * t + 2], a3 = cur[4 * t + 3];
        unsigned int tsum = a0 + a1 + a2 + a3;
        unsigned int x = tsum;
        #pragma unroll
        for (int off = 1; off < 64; off <<= 1) {
            unsigned int y = (unsigned int)__shfl_up((int)x, off);
            if (lane >= off) x += y;
        }
        if (lane == 63) wsum[wid] = x;
        __syncthreads();
        unsigned int wbase = 0;
        for (int w = 0; w < wid; ++w) wbase += wsum[w];
        unsigned int e0x = wbase + x - tsum;      // exclusive prefix of bin 4t
        unsigned int e1x = e0x + a0, e2x = e1x + a1, e3x = e2x + a2;
        cur[4 * t] = e0x; cur[4 * t + 1] = e1x; cur[4 * t + 2] = e2x; cur[4 * t + 3] = e3x;
        if (t == 255) s_total = e3x + a3;         // inclusive total (= #active entries)
        unsigned short* row = offs + (size_t)k * OROW;
        if (4 * t     <= NB) row[4 * t]     = (unsigned short)e0x;
        if (4 * t + 1 <= NB) row[4 * t + 1] = (unsigned short)e1x;
        if (4 * t + 2 <= NB) row[4 * t + 2] = (unsigned short)e2x;
        if (4 * t + 3 <= NB) row[4 * t + 3] = (unsigned short)e3x;
    }
    __syncthreads();

    // pass 2: scatter from registers; entry = 12-bit chunk-local v | sign<<12
#define SCAT1(G) do {                                                              \
    unsigned long long g = (G);                                                    \
    if ((long long)g < 0) {                                                        \
        unsigned int v0 = (unsigned int)(g & 0xFFFFFu);                            \
        unsigned int v1 = (unsigned int)((g >> 20) & 0xFFFFFu);                    \
        unsigned int v2 = (unsigned int)((g >> 40) & 0xFFFFFu);                    \
        unsigned int sl0 = atomicAdd(&cur[v0 >> BIN_BITS], 1u);                    \
        st[sl0] = (unsigned short)((v0 & (CH_SIZE-1)) | ((unsigned int)((g >> 60) & 1u) << CH_BITS)); \
        unsigned int sl1 = atomicAdd(&cur[v1 >> BIN_BITS], 1u);                    \
        st[sl1] = (unsigned short)((v1 & (CH_SIZE-1)) | ((unsigned int)((g >> 61) & 1u) << CH_BITS)); \
        unsigned int sl2 = atomicAdd(&cur[v2 >> BIN_BITS], 1u);                    \
        st[sl2] = (unsigned short)((v2 & (CH_SIZE-1)) | ((unsigned int)((g >> 62) & 1u) << CH_BITS)); \
    }                                                                              \
} while (0)
    if (has0) { SCAT1(q0a); SCAT1(q0b); SCAT1(q0c); SCAT1(q0d); }
    if (has1) { SCAT1(q1a); SCAT1(q1b); SCAT1(q1c); SCAT1(q1d); }
    if (has2) { SCAT1(q2a); SCAT1(q2b); SCAT1(q2c); SCAT1(q2d); }
#undef SCAT1
    __syncthreads();

    // coalesced flush: LDS region -> global, 16B vectors (slack beyond total never read)
    {
        const int tot = (int)s_total;
        const int nvec = (tot + 7) >> 3;               // 8 u16 per int4
        int4* __restrict__ dst = (int4*)(sorted + (size_t)k * RSTRIDE);  // RSTRIDE*2 % 16 == 0
        const int4* __restrict__ src = (const int4*)st;
        for (int i = t; i < nvec; i += 256) dst[i] = src[i];
    }
}

// 4-var-granular dirty mask from a 64-bit singles word: bit j = (nibble j of m) != 0
__device__ __forceinline__ unsigned short subdirty4(unsigned long long m) {
    unsigned int r = 0;
    #pragma unroll
    for (int j = 0; j < 16; ++j)
        r |= (((m >> (4 * j)) & 0xFull) ? 1u : 0u) << j;
    return (unsigned short)r;
}

// ---- per-chunk (4096 vars) accumulate + decode + tmp/tgrp zeroing epilogue ----
__global__ __launch_bounds__(1024) void k_accum(
    const unsigned short* __restrict__ offs,     // [SBLK][OROW]
    const unsigned short* __restrict__ sorted,
    const float* __restrict__ avars,
    unsigned int* __restrict__ packed,
    unsigned long long* __restrict__ avm,
    unsigned long long* __restrict__ svm,
    unsigned short* __restrict__ sgrp4,
    unsigned int* __restrict__ tmp,
    unsigned char* __restrict__ tgrp)
{
    __shared__ unsigned int acc[CH_SIZE];        // 16 KB
    __shared__ unsigned short row0[SBLK];        // 4 KB
    __shared__ unsigned short row1[SBLK];        // 4 KB
    const int c = blockIdx.x;                    // chunk 0..244 (4 fine bins each)
    const int r0 = 4 * c;
    const int r1 = (4 * c + 4 < NB) ? (4 * c + 4) : NB;
    for (int i = threadIdx.x; i < CH_SIZE; i += 1024) acc[i] = 0u;
    for (int i = threadIdx.x; i < SBLK; i += 1024) {   // strided gather of 2 offs columns
        row0[i] = offs[(size_t)i * OROW + r0];
        row1[i] = offs[(size_t)i * OROW + r1];
    }
    __syncthreads();
    for (int k = threadIdx.x; k < SBLK; k += 1024) {   // 2 regions per thread
        const int s0 = row0[k], s1 = row1[k];
        const unsigned short* seg = sorted + (size_t)k * RSTRIDE;  // 128B-aligned base
        int e = s0;
        for (; e < s1 && (e & 3); ++e) {               // head to 8B alignment
            unsigned int p = seg[e];
            atomicAdd(&acc[p & (CH_SIZE - 1)], 0x10000u | (p >> CH_BITS));
        }
        for (; e + 4 <= s1; e += 4) {                  // 4 entries per u64 load
            unsigned long long q = *(const unsigned long long*)(seg + e);
            #pragma unroll
            for (int j = 0; j < 4; ++j) {
                unsigned int p = (unsigned int)((q >> (16 * j)) & 0xFFFFu);
                atomicAdd(&acc[p & (CH_SIZE - 1)], 0x10000u | (p >> CH_BITS));
            }
        }
        for (; e < s1; ++e) {                          // tail
            unsigned int p = seg[e];
            atomicAdd(&acc[p & (CH_SIZE - 1)], 0x10000u | (p >> CH_BITS));
        }
    }
    __syncthreads();
    const int vbase = c << CH_BITS;
    for (int i = threadIdx.x; i < CH_SIZE; i += 1024) {
        int v = vbase + i;
        bool valid = v < Vn;
        unsigned int p = valid ? acc[i] : 0u;
        bool av = valid && (avars[v] != 0.0f);
        unsigned int cnt = p >> 16, pos = p & 0xFFFFu;
        bool sv = av && (pos == 0u || pos == cnt);    // deg == |sdeg|
        unsigned long long avb = __ballot(av);
        unsigned long long svb = __ballot(sv);
        if (valid) { packed[v] = p; tmp[v] = 0u; }    // tmp zeroed here (rides the pass)
        if ((threadIdx.x & 63) == 0) {                // word index < AVW (chunk-padded)
            avm[v >> 6] = avb;
            svm[v >> 6] = svb;
            sgrp4[v >> 6] = subdirty4(svb);           // 4-var-granular dirty bits
            tgrp[v >> 6] = 0;
        }
    }
}

// ---- iteration: function side. LDS sgrp4 filter then fine bitmask. ----
__device__ __forceinline__ void fire_one(unsigned long long g, int f,
                                         unsigned long long* __restrict__ gpack,
                                         const unsigned int* __restrict__ svm32,
                                         const unsigned short* __restrict__ s4,  // LDS
                                         unsigned int* __restrict__ tmp,
                                         unsigned char* __restrict__ tgrp)
{
    if ((long long)g >= 0) return;               // inactive (bit63 clear)
    unsigned int v0 = (unsigned int)(g & 0xFFFFFu);
    unsigned int v1 = (unsigned int)((g >> 20) & 0xFFFFFu);
    unsigned int v2 = (unsigned int)((g >> 40) & 0xFFFFFu);
    // LDS-resident 4-var-granular filter: no global transactions on the common path
    unsigned int h0 = (unsigned int)(s4[v0 >> 6] >> ((v0 >> 2) & 15u)) & 1u;
    unsigned int h1 = (unsigned int)(s4[v1 >> 6] >> ((v1 >> 2) & 15u)) & 1u;
    unsigned int h2 = (unsigned int)(s4[v2 >> 6] >> ((v2 >> 2) & 15u)) & 1u;
    if (!(h0 | h1 | h2)) return;
    unsigned int hit = ((svm32[v0 >> 5] >> (v0 & 31u)) |
                        (svm32[v1 >> 5] >> (v1 & 31u)) |
                        (svm32[v2 >> 5] >> (v2 & 31u))) & 1u;
    if (!hit) return;
    gpack[f] = g & ~(1ull << 63);                // function deactivates (single_f = 1)
    atomicAdd(&tmp[v0], 0x10000u | (unsigned int)((g >> 60) & 1u));
    atomicAdd(&tmp[v1], 0x10000u | (unsigned int)((g >> 61) & 1u));
    atomicAdd(&tmp[v2], 0x10000u | (unsigned int)((g >> 62) & 1u));
    tgrp[v0 >> 6] = 1; tgrp[v1 >> 6] = 1; tgrp[v2 >> 6] = 1;
}

__global__ __launch_bounds__(256) void k_funcs(unsigned long long* __restrict__ gpack,
                        const unsigned int* __restrict__ svm32,
                        const unsigned short* __restrict__ sgrp4,
                        unsigned int* __restrict__ tmp,
                        unsigned char* __restrict__ tgrp)
{
    __shared__ __align__(16) unsigned short s4[AVW];       // 31.4 KB, AVW % 8 == 0
    for (int i = threadIdx.x; i < AVW / 8; i += 256)
        ((int4*)s4)[i] = ((const int4*)sgrp4)[i];
    __syncthreads();
    const int gid = blockIdx.x * 256 + threadIdx.x;
    const int f = gid * 16;
    if (f >= Fn) return;                                   // Fn % 16 == 0: full groups
    // 8 x 16B loads issued up-front: 128B outstanding per thread
    ulonglong2 g0 = *(const ulonglong2*)(gpack + f);
    ulonglong2 g1 = *(const ulonglong2*)(gpack + f + 2);
    ulonglong2 g2 = *(const ulonglong2*)(gpack + f + 4);
    ulonglong2 g3 = *(const ulonglong2*)(gpack + f + 6);
    ulonglong2 g4 = *(const ulonglong2*)(gpack + f + 8);
    ulonglong2 g5 = *(const ulonglong2*)(gpack + f + 10);
    ulonglong2 g6 = *(const ulonglong2*)(gpack + f + 12);
    ulonglong2 g7 = *(const ulonglong2*)(gpack + f + 14);
    fire_one(g0.x, f,      gpack, svm32, s4, tmp, tgrp);
    fire_one(g0.y, f + 1,  gpack, svm32, s4, tmp, tgrp);
    fire_one(g1.x, f + 2,  gpack, svm32, s4, tmp, tgrp);
    fire_one(g1.y, f + 3,  gpack, svm32, s4, tmp, tgrp);
    fire_one(g2.x, f + 4,  gpack, svm32, s4, tmp, tgrp);
    fire_one(g2.y, f + 5,  gpack, svm32, s4, tmp, tgrp);
    fire_one(g3.x, f + 6,  gpack, svm32, s4, tmp, tgrp);
    fire_one(g3.y, f + 7,  gpack, svm32, s4, tmp, tgrp);
    fire_one(g4.x, f + 8,  gpack, svm32, s4, tmp, tgrp);
    fire_one(g4.y, f + 9,  gpack, svm32, s4, tmp, tgrp);
    fire_one(g5.x, f + 10, gpack, svm32, s4, tmp, tgrp);
    fire_one(g5.y, f + 11, gpack, svm32, s4, tmp, tgrp);
    fire_one(g6.x, f + 12, gpack, svm32, s4, tmp, tgrp);
    fire_one(g6.y, f + 13, gpack, svm32, s4, tmp, tgrp);
    fire_one(g7.x, f + 14, gpack, svm32, s4, tmp, tgrp);
    fire_one(g7.y, f + 15, gpack, svm32, s4, tmp, tgrp);
}

// ---- iteration: variable side. Clean-word early-exit; masks + sgrp4 refresh. ----
__global__ void k_update(unsigned int* __restrict__ packed,
                         unsigned int* __restrict__ tmp,
                         unsigned long long* __restrict__ avm,
                         unsigned long long* __restrict__ svm,
                         unsigned short* __restrict__ sgrp4,
                         unsigned char* __restrict__ tgrp,
                         float* __restrict__ deg, int write_deg)
{
    const int v = blockIdx.x * blockDim.x + threadIdx.x;
    const int lane = threadIdx.x & 63;
    const bool valid = v < Vn;
    unsigned long long avw = 0ull, svw = 0ull;
    unsigned char tg = 0;
    if (valid) {
        avw = avm[v >> 6]; svw = svm[v >> 6];          // wave-broadcast loads
        tg = tgrp[v >> 6];                             // wave-uniform dirty-group byte
    }
    // clean word: no fired updates, no singles to retire -> provably no state change
    if (!write_deg && !tg && svw == 0ull) return;
    const bool av_old = valid && ((avw >> lane) & 1ull);
    const bool sv     = valid && ((svw >> lane) & 1ull);
    const bool av_new = av_old && !sv;                  // av *= (1 - single_v)
    unsigned int p = 0u;
    if (valid) {
        p = packed[v];
        if (tg) {
            unsigned int tp = tmp[v];
            if (tp != 0u) {
                if (av_old) { p -= tp; packed[v] = p; } // deg -= seg*av (field-safe)
                tmp[v] = 0u;
            }
        }
    }
    const unsigned int c = p >> 16, pos = p & 0xFFFFu;
    const bool nsv = av_new && (pos == 0u || pos == c); // next single_v
    unsigned long long nsvb = __ballot(nsv);
    if (lane == 0 && valid) {
        svm[v >> 6] = nsvb;
        avm[v >> 6] = avw & ~svw;
        sgrp4[v >> 6] = subdirty4(nsvb);
        if (tg) tgrp[v >> 6] = 0;
    }
    if (write_deg && valid) deg[v] = (float)c;
}

extern "C" void kernel_launch(void* const* d_in, const int* in_sizes, int n_in,
                              void* d_out, int out_size, void* d_ws, size_t ws_size,
                              hipStream_t stream) {
    const int*   graph_map        = (const int*)d_in[0];   // row0 = vidx
    const float* edge_feature     = (const float*)d_in[1];
    const float* active_variables = (const float*)d_in[2];
    const float* active_functions = (const float*)d_in[3];
    const int* vidx = graph_map;

    float* deg = (float*)d_out;
    char* ws = (char*)d_ws;
    size_t off = 0;
    auto alloc = [&](size_t bytes) -> void* {
        void* p = ws + off; off += (bytes + 255) & ~(size_t)255; return p;
    };
    unsigned long long* gpack = (unsigned long long*)alloc(8ull * Fn);            // 33.6 MB
    unsigned int* packed      = (unsigned int*)alloc(4ull * Vn);                  //  4.0 MB
    unsigned long long* avm   = (unsigned long long*)alloc(8ull * AVW);           //  125 KB
    unsigned long long* svm   = (unsigned long long*)alloc(8ull * AVW);           //  125 KB
    unsigned short* sgrp4     = (unsigned short*)alloc(2ull * AVW);               // 31.4 KB
    unsigned char* tgrp       = (unsigned char*)alloc(AVW);                       // 15.7 KB
    unsigned short* offs      = (unsigned short*)alloc(2ull * SBLK * OROW);       //  4.2 MB
    unsigned short* sorted    = (unsigned short*)alloc(2ull * SBLK * RSTRIDE);    // 25.4 MB
    unsigned int* tmp         = (unsigned int*)alloc(4ull * Vn);                  //  4.0 MB
    // total ~71.5 MB

    const int BS = 256;
    const int gV = (Vn + BS - 1) / BS;
    const int gF16 = (Fn / 16 + BS - 1) / BS;

    k_pack_sort<<<SBLK, 256, 0, stream>>>(vidx, edge_feature, active_functions,
                                          gpack, offs, sorted);
    k_accum<<<NCH, 1024, 0, stream>>>(offs, sorted, active_variables, packed,
                                      avm, svm, sgrp4, tmp, tgrp);
    for (int t = 0; t < Tn; ++t) {
        k_funcs<<<gF16, BS, 0, stream>>>(gpack, (const unsigned int*)svm, sgrp4, tmp, tgrp);
        k_update<<<gV, BS, 0, stream>>>(packed, tmp, avm, svm, sgrp4, tgrp, deg, (t == Tn - 1) ? 1 : 0);
    }
}

// Round 12
// 314.026 us; speedup vs baseline: 1.0635x; 1.0090x over previous
//
#include <hip/hip_runtime.h>

// Peeling propagation on bipartite graph. V=1e6, F=4.2e6, K=3 (edge e -> function e/3).
// T=5. Output: deg (V floats) in d_out.
//
// R20 = best config (R16/R17, 304.6us) consolidated:
//  * k_funcs back to 8 fns/thread grid-stride (R19's 16-wide MLP probe was neutral-neg).
//  * tmp staging ELIMINATED: fire_one applies av-gated atomicSub directly to packed
//    (avm readable during k_funcs -- stable, written by previous k_update; firing is
//    rare ~10-30K/iter so scattered atomics cost ~3MB HBM, not R14's 426MB pathology).
//    k_update becomes read-only on packed; accum epilogue drops tmp zeroing.
// Banked: grid.sync ~240us (R12); BULK scattered global atomics memory-side (R14);
// span-count granularity >=4096 (R18); pack_sort latency-shaped ~63us (R16/R17/R19
// probes all no-op); funcs ~20us insensitive to preload/filter/MLP changes.

static constexpr int Vn = 1000000;
static constexpr int Fn = 4200000;
static constexpr int Tn = 5;

static constexpr int SBLK = 2048;                          // sort blocks / regions
static constexpr int FPB  = 2052;                          // functions/block (mult of 4)
static constexpr int BIN_BITS = 10;                        // fine bin = 1024 vars
static constexpr int BIN_SIZE = 1 << BIN_BITS;
static constexpr int NB  = (Vn + BIN_SIZE - 1) >> BIN_BITS;   // 977 fine bins
static constexpr int NBP = 1024;                           // padded fine-bin count (scan)
static constexpr int CH_BITS = 12;                         // chunk = 4096 vars (accum)
static constexpr int CH_SIZE = 1 << CH_BITS;
static constexpr int NCH = (Vn + CH_SIZE - 1) >> CH_BITS;  // 245 chunks
static constexpr int RCAP = 3 * FPB;                       // 6156 max entries/region
static constexpr int RSTRIDE = (RCAP + 63) & ~63;          // 6208 -> 128B-aligned regions
static constexpr int OROW = 1024;                          // offs row stride (u16)
static constexpr int AVW = NCH * (CH_SIZE / 64);           // 15680 u64 mask words (16B-mult)

// ---- fused pack + histogram + shuffle-scan + register-carried scatter + flush ----
__global__ __launch_bounds__(256) void k_pack_sort(
    const int* __restrict__ vidx, const float* __restrict__ ef,
    const float* __restrict__ afunc,
    unsigned long long* __restrict__ gpack,
    unsigned short* __restrict__ offs,      // [SBLK][OROW] exclusive fine-bin offsets
    unsigned short* __restrict__ sorted)    // [SBLK][RSTRIDE] block-private regions
{
    __shared__ unsigned int cur[NBP];       // pass1: histogram; after scan: cursors
    __shared__ unsigned int wsum[4];
    __shared__ unsigned int s_total;
    __shared__ __align__(16) unsigned short st[RSTRIDE];   // 12.4 KB staged region

    const int k = blockIdx.x;
    const int f0 = k * FPB;
    int n = Fn - f0; if (n < 0) n = 0; if (n > FPB) n = FPB;
    const int n4 = n >> 2;                  // n % 4 == 0 always (Fn, FPB mult of 4)
    const int t = threadIdx.x;

    for (int i = t; i < NBP; i += 256) cur[i] = 0u;
    __syncthreads();

    // pass 1: <=3 quad-iterations per thread; packed words kept in registers.
    const int j0 = t, j1 = t + 256, j2 = t + 512;
    const bool has0 = j0 < n4, has1 = j1 < n4, has2 = j2 < n4;
    unsigned long long q0a=0,q0b=0,q0c=0,q0d=0, q1a=0,q1b=0,q1c=0,q1d=0, q2a=0,q2b=0,q2c=0,q2d=0;

#define PROC(J, QA, QB, QC, QD) do {                                               \
    const int fb = f0 + 4 * (J), e = 3 * fb;                                       \
    int4 va = *(const int4*)(vidx + e);                                            \
    int4 vb = *(const int4*)(vidx + e + 4);                                        \
    int4 vc = *(const int4*)(vidx + e + 8);                                        \
    float4 ea = *(const float4*)(ef + e);                                          \
    float4 eb = *(const float4*)(ef + e + 4);                                      \
    float4 ec = *(const float4*)(ef + e + 8);                                      \
    float4 a4 = *(const float4*)(afunc + fb);                                      \
    int   vv[12] = {va.x,va.y,va.z,va.w,vb.x,vb.y,vb.z,vb.w,vc.x,vc.y,vc.z,vc.w};  \
    float ss[12] = {ea.x,ea.y,ea.z,ea.w,eb.x,eb.y,eb.z,eb.w,ec.x,ec.y,ec.z,ec.w};  \
    float aa[4]  = {a4.x,a4.y,a4.z,a4.w};                                          \
    unsigned long long gq[4];                                                      \
    _Pragma("unroll")                                                              \
    for (int q = 0; q < 4; ++q) {                                                  \
        int v0 = vv[3*q], v1 = vv[3*q+1], v2 = vv[3*q+2];                          \
        unsigned int s0 = ss[3*q]   > 0.0f ? 1u : 0u;                              \
        unsigned int s1 = ss[3*q+1] > 0.0f ? 1u : 0u;                              \
        unsigned int s2 = ss[3*q+2] > 0.0f ? 1u : 0u;                              \
        unsigned int act = aa[q] != 0.0f ? 1u : 0u;                                \
        gq[q] = (unsigned long long)(unsigned int)v0                               \
              | ((unsigned long long)(unsigned int)v1 << 20)                       \
              | ((unsigned long long)(unsigned int)v2 << 40)                       \
              | ((unsigned long long)s0 << 60)                                     \
              | ((unsigned long long)s1 << 61)                                     \
              | ((unsigned long long)s2 << 62)                                     \
              | ((unsigned long long)act << 63);                                   \
        if (act) {                                                                 \
            atomicAdd(&cur[v0 >> BIN_BITS], 1u);                                   \
            atomicAdd(&cur[v1 >> BIN_BITS], 1u);                                   \
            atomicAdd(&cur[v2 >> BIN_BITS], 1u);                                   \
        }                                                                          \
    }                                                                              \
    *(ulonglong2*)(gpack + fb)     = make_ulonglong2(gq[0], gq[1]);                \
    *(ulonglong2*)(gpack + fb + 2) = make_ulonglong2(gq[2], gq[3]);                \
    QA = gq[0]; QB = gq[1]; QC = gq[2]; QD = gq[3];                                \
} while (0)

    if (has0) PROC(j0, q0a, q0b, q0c, q0d);
    if (has1) PROC(j1, q1a, q1b, q1c, q1d);
    if (has2) PROC(j2, q2a, q2b, q2c, q2d);
#undef PROC
    __syncthreads();

    // shuffle-based exclusive scan over 1024 fine bins (256 threads x 4 bins).
    {
        const int lane = t & 63, wid = t >> 6;
        unsigned int a0 = cur[4 * t], a1 = cur[4 * t + 1];
        unsigned int a2 = cur[4 * t + 2], a3 = cur[4 * t + 3];
        unsigned int tsum = a0 + a1 + a2 + a3;
        unsigned int x = tsum;
        #pragma unroll
        for (int off = 1; off < 64; off <<= 1) {
            unsigned int y = (unsigned int)__shfl_up((int)x, off);
            if (lane >= off) x += y;
        }
        if (lane == 63) wsum[wid] = x;
        __syncthreads();
        unsigned int wbase = 0;
        for (int w = 0; w < wid; ++w) wbase += wsum[w];
        unsigned int e0x = wbase + x - tsum;      // exclusive prefix of bin 4t
        unsigned int e1x = e0x + a0, e2x = e1x + a1, e3x = e2x + a2;
        cur[4 * t] = e0x; cur[4 * t + 1] = e1x; cur[4 * t + 2] = e2x; cur[4 * t + 3] = e3x;
        if (t == 255) s_total = e3x + a3;         // inclusive total (= #active entries)
        unsigned short* row = offs + (size_t)k * OROW;
        if (4 * t     <= NB) row[4 * t]     = (unsigned short)e0x;
        if (4 * t + 1 <= NB) row[4 * t + 1] = (unsigned short)e1x;
        if (4 * t + 2 <= NB) row[4 * t + 2] = (unsigned short)e2x;
        if (4 * t + 3 <= NB) row[4 * t + 3] = (unsigned short)e3x;
    }
    __syncthreads();

    // pass 2: scatter from registers; entry = 12-bit chunk-local v | sign<<12
#define SCAT1(G) do {                                                              \
    unsigned long long g = (G);                                                    \
    if ((long long)g < 0) {                                                        \
        unsigned int v0 = (unsigned int)(g & 0xFFFFFu);                            \
        unsigned int v1 = (unsigned int)((g >> 20) & 0xFFFFFu);                    \
        unsigned int v2 = (unsigned int)((g >> 40) & 0xFFFFFu);                    \
        unsigned int sl0 = atomicAdd(&cur[v0 >> BIN_BITS], 1u);                    \
        st[sl0] = (unsigned short)((v0 & (CH_SIZE-1)) | ((unsigned int)((g >> 60) & 1u) << CH_BITS)); \
        unsigned int sl1 = atomicAdd(&cur[v1 >> BIN_BITS], 1u);                    \
        st[sl1] = (unsigned short)((v1 & (CH_SIZE-1)) | ((unsigned int)((g >> 61) & 1u) << CH_BITS)); \
        unsigned int sl2 = atomicAdd(&cur[v2 >> BIN_BITS], 1u);                    \
        st[sl2] = (unsigned short)((v2 & (CH_SIZE-1)) | ((unsigned int)((g >> 62) & 1u) << CH_BITS)); \
    }                                                                              \
} while (0)
    if (has0) { SCAT1(q0a); SCAT1(q0b); SCAT1(q0c); SCAT1(q0d); }
    if (has1) { SCAT1(q1a); SCAT1(q1b); SCAT1(q1c); SCAT1(q1d); }
    if (has2) { SCAT1(q2a); SCAT1(q2b); SCAT1(q2c); SCAT1(q2d); }
#undef SCAT1
    __syncthreads();

    // coalesced flush: LDS region -> global, 16B vectors (slack beyond total never read)
    {
        const int tot = (int)s_total;
        const int nvec = (tot + 7) >> 3;               // 8 u16 per int4
        int4* __restrict__ dst = (int4*)(sorted + (size_t)k * RSTRIDE);  // RSTRIDE*2 % 16 == 0
        const int4* __restrict__ src = (const int4*)st;
        for (int i = t; i < nvec; i += 256) dst[i] = src[i];
    }
}

// 4-var-granular dirty mask from a 64-bit singles word: bit j = (nibble j of m) != 0
__device__ __forceinline__ unsigned short subdirty4(unsigned long long m) {
    unsigned int r = 0;
    #pragma unroll
    for (int j = 0; j < 16; ++j)
        r |= (((m >> (4 * j)) & 0xFull) ? 1u : 0u) << j;
    return (unsigned short)r;
}

// ---- per-chunk (4096 vars) accumulate + decode + tgrp zeroing epilogue ----
__global__ __launch_bounds__(1024) void k_accum(
    const unsigned short* __restrict__ offs,     // [SBLK][OROW]
    const unsigned short* __restrict__ sorted,
    const float* __restrict__ avars,
    unsigned int* __restrict__ packed,
    unsigned long long* __restrict__ avm,
    unsigned long long* __restrict__ svm,
    unsigned short* __restrict__ sgrp4,
    unsigned char* __restrict__ tgrp)
{
    __shared__ unsigned int acc[CH_SIZE];        // 16 KB
    __shared__ unsigned short row0[SBLK];        // 4 KB
    __shared__ unsigned short row1[SBLK];        // 4 KB
    const int c = blockIdx.x;                    // chunk 0..244 (4 fine bins each)
    const int r0 = 4 * c;
    const int r1 = (4 * c + 4 < NB) ? (4 * c + 4) : NB;
    for (int i = threadIdx.x; i < CH_SIZE; i += 1024) acc[i] = 0u;
    for (int i = threadIdx.x; i < SBLK; i += 1024) {   // strided gather of 2 offs columns
        row0[i] = offs[(size_t)i * OROW + r0];
        row1[i] = offs[(size_t)i * OROW + r1];
    }
    __syncthreads();
    for (int k = threadIdx.x; k < SBLK; k += 1024) {   // 2 regions per thread
        const int s0 = row0[k], s1 = row1[k];
        const unsigned short* seg = sorted + (size_t)k * RSTRIDE;  // 128B-aligned base
        int e = s0;
        for (; e < s1 && (e & 3); ++e) {               // head to 8B alignment
            unsigned int p = seg[e];
            atomicAdd(&acc[p & (CH_SIZE - 1)], 0x10000u | (p >> CH_BITS));
        }
        for (; e + 4 <= s1; e += 4) {                  // 4 entries per u64 load
            unsigned long long q = *(const unsigned long long*)(seg + e);
            #pragma unroll
            for (int j = 0; j < 4; ++j) {
                unsigned int p = (unsigned int)((q >> (16 * j)) & 0xFFFFu);
                atomicAdd(&acc[p & (CH_SIZE - 1)], 0x10000u | (p >> CH_BITS));
            }
        }
        for (; e < s1; ++e) {                          // tail
            unsigned int p = seg[e];
            atomicAdd(&acc[p & (CH_SIZE - 1)], 0x10000u | (p >> CH_BITS));
        }
    }
    __syncthreads();
    const int vbase = c << CH_BITS;
    for (int i = threadIdx.x; i < CH_SIZE; i += 1024) {
        int v = vbase + i;
        bool valid = v < Vn;
        unsigned int p = valid ? acc[i] : 0u;
        bool av = valid && (avars[v] != 0.0f);
        unsigned int cnt = p >> 16, pos = p & 0xFFFFu;
        bool sv = av && (pos == 0u || pos == cnt);    // deg == |sdeg|
        unsigned long long avb = __ballot(av);
        unsigned long long svb = __ballot(sv);
        if (valid) packed[v] = p;
        if ((threadIdx.x & 63) == 0) {                // word index < AVW (chunk-padded)
            avm[v >> 6] = avb;
            svm[v >> 6] = svb;
            sgrp4[v >> 6] = subdirty4(svb);           // 4-var-granular dirty bits
            tgrp[v >> 6] = 0;
        }
    }
}

// ---- iteration: function side. LDS sgrp4 filter, fine bitmask, DIRECT packed update. ----
__device__ __forceinline__ void fire_one(unsigned long long g, int f,
                                         unsigned long long* __restrict__ gpack,
                                         const unsigned int* __restrict__ svm32,
                                         const unsigned int* __restrict__ avm32,
                                         const unsigned short* __restrict__ s4,  // LDS
                                         unsigned int* __restrict__ packed,
                                         unsigned char* __restrict__ tgrp)
{
    if ((long long)g >= 0) return;               // inactive (bit63 clear)
    unsigned int v0 = (unsigned int)(g & 0xFFFFFu);
    unsigned int v1 = (unsigned int)((g >> 20) & 0xFFFFFu);
    unsigned int v2 = (unsigned int)((g >> 40) & 0xFFFFFu);
    // LDS-resident 4-var-granular filter: no global transactions on the common path
    unsigned int h0 = (unsigned int)(s4[v0 >> 6] >> ((v0 >> 2) & 15u)) & 1u;
    unsigned int h1 = (unsigned int)(s4[v1 >> 6] >> ((v1 >> 2) & 15u)) & 1u;
    unsigned int h2 = (unsigned int)(s4[v2 >> 6] >> ((v2 >> 2) & 15u)) & 1u;
    if (!(h0 | h1 | h2)) return;
    unsigned int hit = ((svm32[v0 >> 5] >> (v0 & 31u)) |
                        (svm32[v1 >> 5] >> (v1 & 31u)) |
                        (svm32[v2 >> 5] >> (v2 & 31u))) & 1u;
    if (!hit) return;
    gpack[f] = g & ~(1ull << 63);                // function deactivates (single_f = 1)
    // av-gated direct subtraction (avm stable during this dispatch = av_old);
    // firing is rare (~10-30K fns/iter) so scattered atomics are cheap here.
    if ((avm32[v0 >> 5] >> (v0 & 31u)) & 1u)
        atomicSub(&packed[v0], 0x10000u | (unsigned int)((g >> 60) & 1u));
    if ((avm32[v1 >> 5] >> (v1 & 31u)) & 1u)
        atomicSub(&packed[v1], 0x10000u | (unsigned int)((g >> 61) & 1u));
    if ((avm32[v2 >> 5] >> (v2 & 31u)) & 1u)
        atomicSub(&packed[v2], 0x10000u | (unsigned int)((g >> 62) & 1u));
    tgrp[v0 >> 6] = 1; tgrp[v1 >> 6] = 1; tgrp[v2 >> 6] = 1;
}

static constexpr int FBLOCKS = 1024;             // grid-stride blocks (4/CU)

__global__ __launch_bounds__(256) void k_funcs(unsigned long long* __restrict__ gpack,
                        const unsigned int* __restrict__ svm32,
                        const unsigned int* __restrict__ avm32,
                        const unsigned short* __restrict__ sgrp4,
                        unsigned int* __restrict__ packed,
                        unsigned char* __restrict__ tgrp)
{
    __shared__ __align__(16) unsigned short s4[AVW];       // 31.4 KB, AVW % 8 == 0
    for (int i = threadIdx.x; i < AVW / 8; i += 256)
        ((int4*)s4)[i] = ((const int4*)sgrp4)[i];
    __syncthreads();
    const int step = FBLOCKS * 256 * 8;
    for (int f = (blockIdx.x * 256 + threadIdx.x) * 8; f < Fn; f += step) {
        // Fn % 8 == 0: each 8-group is full
        ulonglong2 ga = *(const ulonglong2*)(gpack + f);   // 16B aligned
        ulonglong2 gb = *(const ulonglong2*)(gpack + f + 2);
        ulonglong2 gc = *(const ulonglong2*)(gpack + f + 4);
        ulonglong2 gd = *(const ulonglong2*)(gpack + f + 6);
        fire_one(ga.x, f,     gpack, svm32, avm32, s4, packed, tgrp);
        fire_one(ga.y, f + 1, gpack, svm32, avm32, s4, packed, tgrp);
        fire_one(gb.x, f + 2, gpack, svm32, avm32, s4, packed, tgrp);
        fire_one(gb.y, f + 3, gpack, svm32, avm32, s4, packed, tgrp);
        fire_one(gc.x, f + 4, gpack, svm32, avm32, s4, packed, tgrp);
        fire_one(gc.y, f + 5, gpack, svm32, avm32, s4, packed, tgrp);
        fire_one(gd.x, f + 6, gpack, svm32, avm32, s4, packed, tgrp);
        fire_one(gd.y, f + 7, gpack, svm32, avm32, s4, packed, tgrp);
    }
}

// ---- iteration: variable side. Read-only on packed; clean-word early-exit. ----
__global__ void k_update(const unsigned int* __restrict__ packed,
                         unsigned long long* __restrict__ avm,
                         unsigned long long* __restrict__ svm,
                         unsigned short* __restrict__ sgrp4,
                         unsigned char* __restrict__ tgrp,
                         float* __restrict__ deg, int write_deg)
{
    const int v = blockIdx.x * blockDim.x + threadIdx.x;
    const int lane = threadIdx.x & 63;
    const bool valid = v < Vn;
    unsigned long long avw = 0ull, svw = 0ull;
    unsigned char tg = 0;
    if (valid) {
        avw = avm[v >> 6]; svw = svm[v >> 6];          // wave-broadcast loads
        tg = tgrp[v >> 6];                             // wave-uniform dirty-group byte
    }
    // clean word: no fired subtractions (tg==0), no singles to retire (svw==0)
    // -> provably no state change; masks already consistent.
    if (!write_deg && !tg && svw == 0ull) return;
    const bool av_old = valid && ((avw >> lane) & 1ull);
    const bool sv     = valid && ((svw >> lane) & 1ull);
    const bool av_new = av_old && !sv;                  // av *= (1 - single_v)
    unsigned int p = valid ? packed[v] : 0u;            // post-subtraction state
    const unsigned int c = p >> 16, pos = p & 0xFFFFu;
    const bool nsv = av_new && (pos == 0u || pos == c); // next single_v
    unsigned long long nsvb = __ballot(nsv);
    if (lane == 0 && valid) {
        svm[v >> 6] = nsvb;
        avm[v >> 6] = avw & ~svw;
        sgrp4[v >> 6] = subdirty4(nsvb);
        if (tg) tgrp[v >> 6] = 0;
    }
    if (write_deg && valid) deg[v] = (float)c;
}

extern "C" void kernel_launch(void* const* d_in, const int* in_sizes, int n_in,
                              void* d_out, int out_size, void* d_ws, size_t ws_size,
                              hipStream_t stream) {
    const int*   graph_map        = (const int*)d_in[0];   // row0 = vidx
    const float* edge_feature     = (const float*)d_in[1];
    const float* active_variables = (const float*)d_in[2];
    const float* active_functions = (const float*)d_in[3];
    const int* vidx = graph_map;

    float* deg = (float*)d_out;
    char* ws = (char*)d_ws;
    size_t off = 0;
    auto alloc = [&](size_t bytes) -> void* {
        void* p = ws + off; off += (bytes + 255) & ~(size_t)255; return p;
    };
    unsigned long long* gpack = (unsigned long long*)alloc(8ull * Fn);            // 33.6 MB
    unsigned int* packed      = (unsigned int*)alloc(4ull * Vn);                  //  4.0 MB
    unsigned long long* avm   = (unsigned long long*)alloc(8ull * AVW);           //  125 KB
    unsigned long long* svm   = (unsigned long long*)alloc(8ull * AVW);           //  125 KB
    unsigned short* sgrp4     = (unsigned short*)alloc(2ull * AVW);               // 31.4 KB
    unsigned char* tgrp       = (unsigned char*)alloc(AVW);                       // 15.7 KB
    unsigned short* offs      = (unsigned short*)alloc(2ull * SBLK * OROW);       //  4.2 MB
    unsigned short* sorted    = (unsigned short*)alloc(2ull * SBLK * RSTRIDE);    // 25.4 MB
    // total ~67.5 MB

    const int BS = 256;
    const int gV = (Vn + BS - 1) / BS;

    k_pack_sort<<<SBLK, 256, 0, stream>>>(vidx, edge_feature, active_functions,
                                          gpack, offs, sorted);
    k_accum<<<NCH, 1024, 0, stream>>>(offs, sorted, active_variables, packed,
                                      avm, svm, sgrp4, tgrp);
    for (int t = 0; t < Tn; ++t) {
        k_funcs<<<FBLOCKS, BS, 0, stream>>>(gpack, (const unsigned int*)svm,
                                            (const unsigned int*)avm, sgrp4, packed, tgrp);
        k_update<<<gV, BS, 0, stream>>>(packed, avm, svm, sgrp4, tgrp, deg, (t == Tn - 1) ? 1 : 0);
    }
}

// Round 13
// 305.575 us; speedup vs baseline: 1.0929x; 1.0277x over previous
//
#include <hip/hip_runtime.h>

// Peeling propagation on bipartite graph. V=1e6, F=4.2e6, K=3 (edge e -> function e/3).
// T=5. Output: deg (V floats) in d_out.
//
// R21 = R16 verbatim (304.6us, best measured). Final lock-in after the probe matrix
// completed: every kernel's hypothesized bottleneck was attacked R17-R20 and landed
// neutral/negative. Structural floor arithmetic:
//  * pack_sort ~62us: 25.2M LDS atomics / 256 CU ~= 41us floor (LDS-atomic-throughput
//    bound -- why HBM 24% / VALU 11% both look idle and occupancy probes no-op).
//  * accum ~30us: 500K scattered ~50B spans -> ~100MB line-granular FETCH at ~3TB/s
//    (span-COUNT scaling proven by R18's CH_BITS=11 regression).
//  * funcs x5 ~20us: 33.6MB scan, issue-shaped (MLP/filter/preload probes all no-op).
//  * update x5 ~4us + 12 serial dispatch boundaries (grid.sync 30x worse, R12;
//    frontier-CSR setup costs more than it saves, R11).
// Banked: bulk scattered global atomics are memory-side ~32B HBM write each (R14).

static constexpr int Vn = 1000000;
static constexpr int Fn = 4200000;
static constexpr int Tn = 5;

static constexpr int SBLK = 2048;                          // sort blocks / regions
static constexpr int FPB  = 2052;                          // functions/block (mult of 4)
static constexpr int BIN_BITS = 10;                        // fine bin = 1024 vars
static constexpr int BIN_SIZE = 1 << BIN_BITS;
static constexpr int NB  = (Vn + BIN_SIZE - 1) >> BIN_BITS;   // 977 fine bins
static constexpr int NBP = 1024;                           // padded fine-bin count (scan)
static constexpr int CH_BITS = 12;                         // chunk = 4096 vars
static constexpr int CH_SIZE = 1 << CH_BITS;
static constexpr int NCH = (Vn + CH_SIZE - 1) >> CH_BITS;  // 245 chunks
static constexpr int RCAP = 3 * FPB;                       // 6156 max entries/region
static constexpr int RSTRIDE = (RCAP + 63) & ~63;          // 6208 -> 128B-aligned regions
static constexpr int OROW = 1024;                          // offs row stride (u16)
static constexpr int AVW = NCH * (CH_SIZE / 64);           // 15680 u64 mask words (16B-mult)

// ---- fused pack + histogram + shuffle-scan + LDS-staged scatter + coalesced flush ----
__global__ __launch_bounds__(256) void k_pack_sort(
    const int* __restrict__ vidx, const float* __restrict__ ef,
    const float* __restrict__ afunc,
    unsigned long long* __restrict__ gpack,
    unsigned short* __restrict__ offs,      // [SBLK][OROW] exclusive fine-bin offsets
    unsigned short* __restrict__ sorted)    // [SBLK][RSTRIDE] block-private regions
{
    __shared__ unsigned int cur[NBP];       // pass1: histogram; after scan: cursors
    __shared__ unsigned int wsum[4];
    __shared__ unsigned int s_total;
    __shared__ __align__(16) unsigned short st[RSTRIDE];   // 12.4 KB staged region
    // LDS total ~16.6 KB -> 8 blocks/CU (32 waves)

    const int k = blockIdx.x;
    const int f0 = k * FPB;
    int n = Fn - f0; if (n < 0) n = 0; if (n > FPB) n = FPB;
    const int n4 = n >> 2;                  // n % 4 == 0 always (Fn, FPB mult of 4)

    for (int i = threadIdx.x; i < NBP; i += 256) cur[i] = 0u;
    __syncthreads();

    // pass 1 (4-wide): read vidx/ef/afunc once, emit gpack, histogram fine bins
    for (int j = threadIdx.x; j < n4; j += 256) {
        const int fb = f0 + 4 * j, e = 3 * fb;
        int4 va = *(const int4*)(vidx + e);
        int4 vb = *(const int4*)(vidx + e + 4);
        int4 vc = *(const int4*)(vidx + e + 8);
        float4 ea = *(const float4*)(ef + e);
        float4 eb = *(const float4*)(ef + e + 4);
        float4 ec = *(const float4*)(ef + e + 8);
        float4 a4 = *(const float4*)(afunc + fb);
        int      vv[12] = {va.x, va.y, va.z, va.w, vb.x, vb.y, vb.z, vb.w, vc.x, vc.y, vc.z, vc.w};
        float    ss[12] = {ea.x, ea.y, ea.z, ea.w, eb.x, eb.y, eb.z, eb.w, ec.x, ec.y, ec.z, ec.w};
        float    aa[4]  = {a4.x, a4.y, a4.z, a4.w};
        unsigned long long gq[4];
        #pragma unroll
        for (int q = 0; q < 4; ++q) {
            int v0 = vv[3 * q], v1 = vv[3 * q + 1], v2 = vv[3 * q + 2];
            unsigned int s0 = ss[3 * q]     > 0.0f ? 1u : 0u;
            unsigned int s1 = ss[3 * q + 1] > 0.0f ? 1u : 0u;
            unsigned int s2 = ss[3 * q + 2] > 0.0f ? 1u : 0u;
            unsigned int act = aa[q] != 0.0f ? 1u : 0u;
            gq[q] = (unsigned long long)(unsigned int)v0
                  | ((unsigned long long)(unsigned int)v1 << 20)
                  | ((unsigned long long)(unsigned int)v2 << 40)
                  | ((unsigned long long)s0 << 60)
                  | ((unsigned long long)s1 << 61)
                  | ((unsigned long long)s2 << 62)
                  | ((unsigned long long)act << 63);
            if (act) {
                atomicAdd(&cur[v0 >> BIN_BITS], 1u);
                atomicAdd(&cur[v1 >> BIN_BITS], 1u);
                atomicAdd(&cur[v2 >> BIN_BITS], 1u);
            }
        }
        *(ulonglong2*)(gpack + fb)     = make_ulonglong2(gq[0], gq[1]);
        *(ulonglong2*)(gpack + fb + 2) = make_ulonglong2(gq[2], gq[3]);
    }
    __syncthreads();

    // shuffle-based exclusive scan over 1024 fine bins (256 threads x 4 bins).
    // Each thread reads only its own cur[4t..4t+3] before overwriting them.
    {
        const int t = threadIdx.x, lane = t & 63, wid = t >> 6;
        unsigned int a0 = cur[4 * t], a1 = cur[4 * t + 1];
        unsigned int a2 = cur[4 * t + 2], a3 = cur[4 * t + 3];
        unsigned int tsum = a0 + a1 + a2 + a3;
        unsigned int x = tsum;
        #pragma unroll
        for (int off = 1; off < 64; off <<= 1) {
            unsigned int y = (unsigned int)__shfl_up((int)x, off);
            if (lane >= off) x += y;
        }
        if (lane == 63) wsum[wid] = x;
        __syncthreads();
        unsigned int wbase = 0;
        for (int w = 0; w < wid; ++w) wbase += wsum[w];
        unsigned int e0x = wbase + x - tsum;      // exclusive prefix of bin 4t
        unsigned int e1x = e0x + a0, e2x = e1x + a1, e3x = e2x + a2;
        cur[4 * t] = e0x; cur[4 * t + 1] = e1x; cur[4 * t + 2] = e2x; cur[4 * t + 3] = e3x;
        if (t == 255) s_total = e3x + a3;         // inclusive total (= #active entries)
        unsigned short* row = offs + (size_t)k * OROW;
        if (4 * t     <= NB) row[4 * t]     = (unsigned short)e0x;
        if (4 * t + 1 <= NB) row[4 * t + 1] = (unsigned short)e1x;
        if (4 * t + 2 <= NB) row[4 * t + 2] = (unsigned short)e2x;
        if (4 * t + 3 <= NB) row[4 * t + 3] = (unsigned short)e3x;
    }
    __syncthreads();

    // pass 2 (4-wide): re-read gpack (L2-hot) and scatter into LDS region;
    // entry = 12-bit chunk-local v | sign<<12
    for (int j = threadIdx.x; j < n4; j += 256) {
        const int fb = f0 + 4 * j;
        ulonglong2 ga = *(const ulonglong2*)(gpack + fb);
        ulonglong2 gb = *(const ulonglong2*)(gpack + fb + 2);
        unsigned long long gq[4] = {ga.x, ga.y, gb.x, gb.y};
        #pragma unroll
        for (int q = 0; q < 4; ++q) {
            unsigned long long g = gq[q];
            if ((long long)g < 0) {
                unsigned int v0 = (unsigned int)(g & 0xFFFFFu);
                unsigned int v1 = (unsigned int)((g >> 20) & 0xFFFFFu);
                unsigned int v2 = (unsigned int)((g >> 40) & 0xFFFFFu);
                unsigned int sl0 = atomicAdd(&cur[v0 >> BIN_BITS], 1u);
                st[sl0] = (unsigned short)((v0 & (CH_SIZE - 1)) | ((unsigned int)((g >> 60) & 1u) << CH_BITS));
                unsigned int sl1 = atomicAdd(&cur[v1 >> BIN_BITS], 1u);
                st[sl1] = (unsigned short)((v1 & (CH_SIZE - 1)) | ((unsigned int)((g >> 61) & 1u) << CH_BITS));
                unsigned int sl2 = atomicAdd(&cur[v2 >> BIN_BITS], 1u);
                st[sl2] = (unsigned short)((v2 & (CH_SIZE - 1)) | ((unsigned int)((g >> 62) & 1u) << CH_BITS));
            }
        }
    }
    __syncthreads();

    // coalesced flush: LDS region -> global, 16B vectors (slack beyond total never read)
    {
        const int tot = (int)s_total;
        const int nvec = (tot + 7) >> 3;               // 8 u16 per int4
        int4* __restrict__ dst = (int4*)(sorted + (size_t)k * RSTRIDE);  // RSTRIDE*2 % 16 == 0
        const int4* __restrict__ src = (const int4*)st;
        for (int i = threadIdx.x; i < nvec; i += 256) dst[i] = src[i];
    }
}

// sub-byte dirty mask from a 64-bit singles word: bit j = (byte j of m) != 0
__device__ __forceinline__ unsigned char subdirty8(unsigned long long m) {
    unsigned char b = 0;
    #pragma unroll
    for (int j = 0; j < 8; ++j) b |= (unsigned char)((((m >> (8 * j)) & 0xFFull) ? 1u : 0u) << j);
    return b;
}

// ---- per-chunk accumulate + decode + tmp/tgrp zeroing epilogue (offs read direct) ----
__global__ __launch_bounds__(1024) void k_accum(
    const unsigned short* __restrict__ offs,     // [SBLK][OROW]
    const unsigned short* __restrict__ sorted,
    const float* __restrict__ avars,
    unsigned int* __restrict__ packed,
    unsigned long long* __restrict__ avm,
    unsigned long long* __restrict__ svm,
    unsigned char* __restrict__ sgrp8,
    unsigned int* __restrict__ tmp,
    unsigned char* __restrict__ tgrp)
{
    __shared__ unsigned int acc[CH_SIZE];        // 16 KB
    __shared__ unsigned short row0[SBLK];        // 4 KB
    __shared__ unsigned short row1[SBLK];        // 4 KB
    const int c = blockIdx.x;                    // chunk 0..244
    const int r0 = 4 * c;
    const int r1 = (4 * c + 4 < NB) ? (4 * c + 4) : NB;
    for (int i = threadIdx.x; i < CH_SIZE; i += 1024) acc[i] = 0u;
    for (int i = threadIdx.x; i < SBLK; i += 1024) {   // strided gather of 2 offs columns
        row0[i] = offs[(size_t)i * OROW + r0];
        row1[i] = offs[(size_t)i * OROW + r1];
    }
    __syncthreads();
    for (int k = threadIdx.x; k < SBLK; k += 1024) {   // 2 regions per thread
        const int s0 = row0[k], s1 = row1[k];
        const unsigned short* seg = sorted + (size_t)k * RSTRIDE;  // 128B-aligned base
        int e = s0;
        for (; e < s1 && (e & 3); ++e) {               // head to 8B alignment
            unsigned int p = seg[e];
            atomicAdd(&acc[p & (CH_SIZE - 1)], 0x10000u | (p >> CH_BITS));
        }
        for (; e + 4 <= s1; e += 4) {                  // 4 entries per u64 load
            unsigned long long q = *(const unsigned long long*)(seg + e);
            #pragma unroll
            for (int j = 0; j < 4; ++j) {
                unsigned int p = (unsigned int)((q >> (16 * j)) & 0xFFFFu);
                atomicAdd(&acc[p & (CH_SIZE - 1)], 0x10000u | (p >> CH_BITS));
            }
        }
        for (; e < s1; ++e) {                          // tail
            unsigned int p = seg[e];
            atomicAdd(&acc[p & (CH_SIZE - 1)], 0x10000u | (p >> CH_BITS));
        }
    }
    __syncthreads();
    const int vbase = c << CH_BITS;
    for (int i = threadIdx.x; i < CH_SIZE; i += 1024) {
        int v = vbase + i;
        bool valid = v < Vn;
        unsigned int p = valid ? acc[i] : 0u;
        bool av = valid && (avars[v] != 0.0f);
        unsigned int cnt = p >> 16, pos = p & 0xFFFFu;
        bool sv = av && (pos == 0u || pos == cnt);    // deg == |sdeg|
        unsigned long long avb = __ballot(av);
        unsigned long long svb = __ballot(sv);
        if (valid) { packed[v] = p; tmp[v] = 0u; }    // tmp zeroed here (rides the pass)
        if ((threadIdx.x & 63) == 0) {                // word index < AVW (chunk-padded)
            avm[v >> 6] = avb;
            svm[v >> 6] = svb;
            sgrp8[v >> 6] = subdirty8(svb);           // 8-var-granular dirty bits
            tgrp[v >> 6] = 0;
        }
    }
}

// ---- iteration: function side. LDS sgrp8 filter then fine bitmask. ----
__device__ __forceinline__ void fire_one(unsigned long long g, int f,
                                         unsigned long long* __restrict__ gpack,
                                         const unsigned int* __restrict__ svm32,
                                         const unsigned char* __restrict__ s8,   // LDS
                                         unsigned int* __restrict__ tmp,
                                         unsigned char* __restrict__ tgrp)
{
    if ((long long)g >= 0) return;               // inactive (bit63 clear)
    unsigned int v0 = (unsigned int)(g & 0xFFFFFu);
    unsigned int v1 = (unsigned int)((g >> 20) & 0xFFFFFu);
    unsigned int v2 = (unsigned int)((g >> 40) & 0xFFFFFu);
    // LDS-resident 8-var-granular filter: no global transactions on the common path
    unsigned int h0 = (unsigned int)(s8[v0 >> 6] >> ((v0 >> 3) & 7u)) & 1u;
    unsigned int h1 = (unsigned int)(s8[v1 >> 6] >> ((v1 >> 3) & 7u)) & 1u;
    unsigned int h2 = (unsigned int)(s8[v2 >> 6] >> ((v2 >> 3) & 7u)) & 1u;
    if (!(h0 | h1 | h2)) return;
    unsigned int hit = ((svm32[v0 >> 5] >> (v0 & 31u)) |
                        (svm32[v1 >> 5] >> (v1 & 31u)) |
                        (svm32[v2 >> 5] >> (v2 & 31u))) & 1u;
    if (!hit) return;
    gpack[f] = g & ~(1ull << 63);                // function deactivates (single_f = 1)
    atomicAdd(&tmp[v0], 0x10000u | (unsigned int)((g >> 60) & 1u));
    atomicAdd(&tmp[v1], 0x10000u | (unsigned int)((g >> 61) & 1u));
    atomicAdd(&tmp[v2], 0x10000u | (unsigned int)((g >> 62) & 1u));
    tgrp[v0 >> 6] = 1; tgrp[v1 >> 6] = 1; tgrp[v2 >> 6] = 1;
}

static constexpr int FBLOCKS = 1024;             // grid-stride blocks (4/CU)

__global__ __launch_bounds__(256) void k_funcs(unsigned long long* __restrict__ gpack,
                        const unsigned int* __restrict__ svm32,
                        const unsigned char* __restrict__ sgrp8,
                        unsigned int* __restrict__ tmp,
                        unsigned char* __restrict__ tgrp)
{
    __shared__ __align__(16) unsigned char s8[AVW];        // 15.7 KB, AVW % 16 == 0
    for (int i = threadIdx.x; i < AVW / 16; i += 256)
        ((int4*)s8)[i] = ((const int4*)sgrp8)[i];
    __syncthreads();
    const int step = FBLOCKS * 256 * 8;
    for (int f = (blockIdx.x * 256 + threadIdx.x) * 8; f < Fn; f += step) {
        // Fn % 8 == 0: each 8-group is full
        ulonglong2 ga = *(const ulonglong2*)(gpack + f);   // 16B aligned
        ulonglong2 gb = *(const ulonglong2*)(gpack + f + 2);
        ulonglong2 gc = *(const ulonglong2*)(gpack + f + 4);
        ulonglong2 gd = *(const ulonglong2*)(gpack + f + 6);
        fire_one(ga.x, f,     gpack, svm32, s8, tmp, tgrp);
        fire_one(ga.y, f + 1, gpack, svm32, s8, tmp, tgrp);
        fire_one(gb.x, f + 2, gpack, svm32, s8, tmp, tgrp);
        fire_one(gb.y, f + 3, gpack, svm32, s8, tmp, tgrp);
        fire_one(gc.x, f + 4, gpack, svm32, s8, tmp, tgrp);
        fire_one(gc.y, f + 5, gpack, svm32, s8, tmp, tgrp);
        fire_one(gd.x, f + 6, gpack, svm32, s8, tmp, tgrp);
        fire_one(gd.y, f + 7, gpack, svm32, s8, tmp, tgrp);
    }
}

// ---- iteration: variable side. Clean-word early-exit; masks + sgrp8 refresh. ----
__global__ void k_update(unsigned int* __restrict__ packed,
                         unsigned int* __restrict__ tmp,
                         unsigned long long* __restrict__ avm,
                         unsigned long long* __restrict__ svm,
                         unsigned char* __restrict__ sgrp8,
                         unsigned char* __restrict__ tgrp,
                         float* __restrict__ deg, int write_deg)
{
    const int v = blockIdx.x * blockDim.x + threadIdx.x;
    const int lane = threadIdx.x & 63;
    const bool valid = v < Vn;
    unsigned long long avw = 0ull, svw = 0ull;
    unsigned char tg = 0;
    if (valid) {
        avw = avm[v >> 6]; svw = svm[v >> 6];          // wave-broadcast loads
        tg = tgrp[v >> 6];                             // wave-uniform dirty-group byte
    }
    // clean word: no fired updates, no singles to retire -> provably no state change
    if (!write_deg && !tg && svw == 0ull) return;
    const bool av_old = valid && ((avw >> lane) & 1ull);
    const bool sv     = valid && ((svw >> lane) & 1ull);
    const bool av_new = av_old && !sv;                  // av *= (1 - single_v)
    unsigned int p = 0u;
    if (valid) {
        p = packed[v];
        if (tg) {
            unsigned int tp = tmp[v];
            if (tp != 0u) {
                if (av_old) { p -= tp; packed[v] = p; } // deg -= seg*av (field-safe)
                tmp[v] = 0u;
            }
        }
    }
    const unsigned int c = p >> 16, pos = p & 0xFFFFu;
    const bool nsv = av_new && (pos == 0u || pos == c); // next single_v
    unsigned long long nsvb = __ballot(nsv);
    if (lane == 0 && valid) {
        svm[v >> 6] = nsvb;
        avm[v >> 6] = avw & ~svw;
        sgrp8[v >> 6] = subdirty8(nsvb);
        if (tg) tgrp[v >> 6] = 0;
    }
    if (write_deg && valid) deg[v] = (float)c;
}

extern "C" void kernel_launch(void* const* d_in, const int* in_sizes, int n_in,
                              void* d_out, int out_size, void* d_ws, size_t ws_size,
                              hipStream_t stream) {
    const int*   graph_map        = (const int*)d_in[0];   // row0 = vidx
    const float* edge_feature     = (const float*)d_in[1];
    const float* active_variables = (const float*)d_in[2];
    const float* active_functions = (const float*)d_in[3];
    const int* vidx = graph_map;

    float* deg = (float*)d_out;
    char* ws = (char*)d_ws;
    size_t off = 0;
    auto alloc = [&](size_t bytes) -> void* {
        void* p = ws + off; off += (bytes + 255) & ~(size_t)255; return p;
    };
    unsigned long long* gpack = (unsigned long long*)alloc(8ull * Fn);            // 33.6 MB
    unsigned int* packed      = (unsigned int*)alloc(4ull * Vn);                  //  4.0 MB
    unsigned long long* avm   = (unsigned long long*)alloc(8ull * AVW);           //  125 KB
    unsigned long long* svm   = (unsigned long long*)alloc(8ull * AVW);           //  125 KB
    unsigned char* sgrp8      = (unsigned char*)alloc(AVW);                       // 15.7 KB
    unsigned char* tgrp       = (unsigned char*)alloc(AVW);                       // 15.7 KB
    unsigned short* offs      = (unsigned short*)alloc(2ull * SBLK * OROW);       //  4.2 MB
    unsigned short* sorted    = (unsigned short*)alloc(2ull * SBLK * RSTRIDE);    // 25.4 MB
    unsigned int* tmp         = (unsigned int*)alloc(4ull * Vn);                  //  4.0 MB
    // total ~71.5 MB

    const int BS = 256;
    const int gV = (Vn + BS - 1) / BS;

    k_pack_sort<<<SBLK, 256, 0, stream>>>(vidx, edge_feature, active_functions,
                                          gpack, offs, sorted);
    k_accum<<<NCH, 1024, 0, stream>>>(offs, sorted, active_variables, packed,
                                      avm, svm, sgrp8, tmp, tgrp);
    for (int t = 0; t < Tn; ++t) {
        k_funcs<<<FBLOCKS, BS, 0, stream>>>(gpack, (const unsigned int*)svm, sgrp8, tmp, tgrp);
        k_update<<<gV, BS, 0, stream>>>(packed, tmp, avm, svm, sgrp8, tgrp, deg, (t == Tn - 1) ? 1 : 0);
    }
}